// Round 5
// baseline (776.425 us; speedup 1.0000x reference)
//
#include <hip/hip_runtime.h>
#include <hip/hip_bf16.h>

#define M_DIM 4096
#define N_DIM 8192
#define K_DIM 8192

using bf16x8 = __attribute__((ext_vector_type(8))) short;
using f32x4  = __attribute__((ext_vector_type(4))) float;
using f32x16 = __attribute__((ext_vector_type(16))) float;

static __device__ __forceinline__ unsigned short f32_to_bf16_rne(float f) {
    unsigned u = __float_as_uint(f);
    unsigned rounding = 0x7FFFu + ((u >> 16) & 1u);
    u += rounding;
    return (unsigned short)(u >> 16);
}

// ---------------- zero W (f32) ----------------
__global__ void zero_kernel(float4* __restrict__ p, int n4) {
    int i = blockIdx.x * blockDim.x + threadIdx.x;
    int stride = gridDim.x * blockDim.x;
    float4 z = make_float4(0.f, 0.f, 0.f, 0.f);
    for (; i < n4; i += stride) p[i] = z;
}

// ---------------- scatter-add COO ----------------
__global__ void scatter_kernel(const float* __restrict__ vals,
                               const int* __restrict__ rows,
                               const int* __restrict__ cols,
                               float* __restrict__ W, int n) {
    int i = blockIdx.x * blockDim.x + threadIdx.x;
    if (i < n) {
        atomicAdd(&W[(size_t)rows[i] * K_DIM + cols[i]], vals[i]);
    }
}

// ---------------- f32 -> bf16 cast ----------------
__global__ void cvt_bf16_kernel(const float4* __restrict__ src,
                                ushort4* __restrict__ dst, int n4) {
    int i = blockIdx.x * blockDim.x + threadIdx.x;
    int stride = gridDim.x * blockDim.x;
    for (; i < n4; i += stride) {
        float4 v = src[i];
        ushort4 o;
        o.x = f32_to_bf16_rne(v.x);
        o.y = f32_to_bf16_rne(v.y);
        o.z = f32_to_bf16_rne(v.z);
        o.w = f32_to_bf16_rne(v.w);
        dst[i] = o;
    }
}

// ---------------- zero d_out fallback (ws too small diagnostic) ----------------
__global__ void zero_out_kernel(float* __restrict__ p, int n) {
    int i = blockIdx.x * blockDim.x + threadIdx.x;
    int stride = gridDim.x * blockDim.x;
    for (; i < n; i += stride) p[i] = 0.f;
}

// ---------------- bf16 NT GEMM, 256x256 8-phase, 32x32x16 MFMA ----------------
// C[M][N] = A[M][K] * B[N][K]^T.  BM=BN=256, BK=64, 8 waves (2M x 4N),
// per-wave output 128x64 as acc[4 mfrag][2 nfrag] f32x16.  LDS 128 KiB
// double-buffered: [db][A/B][half 128 rows][128][64] bf16.
// Phase = K-step s (4 per tile): {ds_read af[4] (+8 B frags at s=0, B is
// register-resident for the whole tile) | stage 1 half-tile | barrier |
// lgkmcnt(0) | setprio(1) 8 independent 32x32x16 MFMA setprio(0) |
// (boundary vmcnt) | barrier}.  Staging (liveness-verified):
//   s0: A(t+1) h0 -> db^1   s1: A(t+1) h1 -> db^1
//   s2: B(t+2) h0 -> db     s3: B(t+2) h1 -> db   (B[db] dead after s0)
// Boundary vmcnt(4) leaves exactly the B(t+2) pair in flight (T4).
//
// LDS swizzle (T2, rule #21), r4-fix: slot (row,c) holds global k-chunk
// c ^ S(row) with S(row) = (row&7) ^ (((row>>3)&3)<<1).  The r4 version
// (S = row&7 only) was 4-way conflicted under the 32x32 read pattern:
// lanes {l,l+8,l+16,l+24} share lane&7 AND lane>>5, so all four hit one
// bank-quad (measured 5.03e7 = 4.0 extra cyc/read).  Adding the
// ((row>>3)&3)<<1 term makes the quad vary across both strided-8 and
// consecutive-8 lane groups (8 distinct quads each).  Read rows are
// m*32+lr32, so S(row) collapses to the lane constant
// sx2 = (lr32&7) ^ (((lr32>>3)&3)<<1).  Staging pre-swizzles the global
// source with the same involution; coalescing preserved (each 8-lane
// row-group covers one permuted 128B segment).
// 32x32x16 frag layout: A lane l, reg j = A[row=l&31][k=(l>>5)*8+j]; B
// symmetric; C/D col=lane&31, row=(reg&3)+8*(reg>>2)+4*(lane>>5) [m74/m101].
__global__ __launch_bounds__(512, 2) void gemm_bt(const ushort* __restrict__ A,
                                                  const ushort* __restrict__ B,
                                                  float* __restrict__ C) {
    constexpr int BK = 64;
    constexpr int NT = K_DIM / BK;     // 128 K-tiles
    __shared__ ushort lds[65536];      // 128 KiB

    const int nbn = N_DIM / 256;       // 32
    const int bm = blockIdx.x / nbn;
    const int bn = blockIdx.x % nbn;
    const int brow = bm * 256, bcol = bn * 256;

    const int t    = threadIdx.x;
    const int lane = t & 63;
    const int wid  = t >> 6;           // 0..7
    const int wm   = wid >> 2;         // 0..1 (M half)
    const int wn   = wid & 3;          // 0..3 (N quarter)
    const int lr32 = lane & 31;        // row/col within 32x32 frag
    const int ghi  = lane >> 5;        // 0..1 (k-half of frag)
    // read-side swizzle constant: S(row) for row = anything*32 + lr32
    const int sx2  = (lr32 & 7) ^ (((lr32 >> 3) & 3) << 1);

    f32x16 acc[4][2] = {};
    bf16x8 bfr[2][4];                  // B frags [nfrag][kstep], tile-resident

    // stage one 128x64 half-tile: 512 thr x 2 x 16B. Linear LDS dest,
    // source k-chunk pre-swizzled: (fl&7) ^ S(fl>>3).
    auto stage_half = [&](int db, int op, int half, int ktile) {
        const ushort* G = (op == 0) ? A : B;
        const int rbase = ((op == 0) ? brow : bcol) + half * 128;
        #pragma unroll
        for (int i = 0; i < 2; ++i) {
            int fl  = i * 512 + t;                 // 0..1023
            int row = fl >> 3;
            int cc  = (fl & 7) ^ (row & 7) ^ (((row >> 3) & 3) << 1);
            const ushort* src = G + (size_t)(rbase + row) * K_DIM + ktile * BK + cc * 8;
            __builtin_amdgcn_global_load_lds(
                (const __attribute__((address_space(1))) void*)src,
                (__attribute__((address_space(3))) void*)
                    (&lds[db * 32768 + op * 16384 + half * 8192 + fl * 8]),
                16, 0, 0);
        }
    };

    auto tile_body = [&](int tt, int db, bool stgA, bool stgB, int vm) {
        // per-wave LDS bases (element offsets into ushort lds[])
        const ushort* Ah = &lds[db * 32768 + wm * 8192];
        const ushort* Bh = &lds[db * 32768 + 16384 + (wn >> 1) * 8192 + (wn & 1) * 4096];
        #pragma unroll
        for (int s = 0; s < 4; ++s) {
            const int sc = (2 * s + ghi) ^ sx2;    // swizzled k-chunk this step
            bf16x8 af[4];
            if (s == 0) {
                #pragma unroll
                for (int n = 0; n < 2; ++n)
                    #pragma unroll
                    for (int ss = 0; ss < 4; ++ss) {
                        const int scb = (2 * ss + ghi) ^ sx2;
                        bfr[n][ss] = *(const bf16x8*)(Bh + (n * 32 + lr32) * 64 + scb * 8);
                    }
            }
            #pragma unroll
            for (int m = 0; m < 4; ++m)
                af[m] = *(const bf16x8*)(Ah + (m * 32 + lr32) * 64 + sc * 8);

            if (s == 0 && stgA) stage_half(db ^ 1, 0, 0, tt + 1);
            if (s == 1 && stgA) stage_half(db ^ 1, 0, 1, tt + 1);
            if (s == 2 && stgB) stage_half(db,     1, 0, tt + 2);
            if (s == 3 && stgB) stage_half(db,     1, 1, tt + 2);
            __builtin_amdgcn_s_barrier();
            asm volatile("s_waitcnt lgkmcnt(0)" ::: "memory");
            __builtin_amdgcn_s_setprio(1);
            #pragma unroll
            for (int m = 0; m < 4; ++m)
                #pragma unroll
                for (int n = 0; n < 2; ++n)
                    acc[m][n] = __builtin_amdgcn_mfma_f32_32x32x16_bf16(
                        af[m], bfr[n][s], acc[m][n], 0, 0, 0);
            __builtin_amdgcn_s_setprio(0);
            if (s == 3) {
                if (vm == 4) asm volatile("s_waitcnt vmcnt(4)" ::: "memory");
                else         asm volatile("s_waitcnt vmcnt(0)" ::: "memory");
            }
            __builtin_amdgcn_s_barrier();
        }
    };

    // ---- prologue: tile 0 fully + B(1); drain to 4 (B(1) stays in flight) ----
    stage_half(0, 0, 0, 0);
    stage_half(0, 0, 1, 0);
    stage_half(0, 1, 0, 0);
    stage_half(0, 1, 1, 0);
    stage_half(1, 1, 0, 1);
    stage_half(1, 1, 1, 1);
    asm volatile("s_waitcnt vmcnt(4)" ::: "memory");
    __builtin_amdgcn_s_barrier();

    // ---- main loop: tiles 0..NT-3 with full staging, vmcnt(4) ----
    for (int tt = 0; tt < NT - 2; tt += 2) {
        tile_body(tt,     0, true, true, 4);
        tile_body(tt + 1, 1, true, true, 4);
    }
    // ---- peeled tail: NT-2 stages A(NT-1) only then drains; NT-1 bare ----
    tile_body(NT - 2, 0, true,  false, 0);
    tile_body(NT - 1, 1, false, false, 0);

    // ---- epilogue: C/D col=lane&31, row=(reg&3)+8*(reg>>2)+4*(lane>>5) ----
    #pragma unroll
    for (int m = 0; m < 4; ++m) {
        #pragma unroll
        for (int n = 0; n < 2; ++n) {
            const int col   = bcol + wn * 64 + n * 32 + lr32;
            const int rbase = brow + wm * 128 + m * 32 + 4 * ghi;
            #pragma unroll
            for (int r = 0; r < 16; ++r) {
                int row = rbase + (r & 3) + 8 * (r >> 2);
                C[(size_t)row * N_DIM + col] = acc[m][n][r];
            }
        }
    }
}

extern "C" void kernel_launch(void* const* d_in, const int* in_sizes, int n_in,
                              void* d_out, int out_size, void* d_ws, size_t ws_size,
                              hipStream_t stream) {
    const float* x    = (const float*)d_in[0];
    const float* vals = (const float*)d_in[1];
    const int* rows   = (const int*)d_in[2];
    const int* cols   = (const int*)d_in[3];
    float* out        = (float*)d_out;
    const int n_items = in_sizes[1];

    const size_t W_F32_BYTES  = (size_t)N_DIM * K_DIM * 4;  // 256 MiB
    const size_t W_BF16_BYTES = (size_t)N_DIM * K_DIM * 2;  // 128 MiB
    const size_t X_BF16_BYTES = (size_t)M_DIM * K_DIM * 2;  //  64 MiB
    const size_t NEEDED = W_F32_BYTES + W_BF16_BYTES + X_BF16_BYTES;

    if (ws_size < NEEDED) {
        // Diagnostic fallback: clean absmax=126 failure signals ws too small.
        zero_out_kernel<<<2048, 256, 0, stream>>>(out, out_size);
        return;
    }

    char* ws = (char*)d_ws;
    float* Wf  = (float*)ws;
    ushort* Wb = (ushort*)(ws + W_F32_BYTES);
    ushort* Xb = (ushort*)(ws + W_F32_BYTES + W_BF16_BYTES);

    // 1) zero W (re-zeroed every call: deterministic under replay)
    zero_kernel<<<2048, 256, 0, stream>>>((float4*)Wf, (N_DIM * K_DIM) / 4);
    // 2) scatter-add nonzeros
    scatter_kernel<<<(n_items + 255) / 256, 256, 0, stream>>>(vals, rows, cols, Wf, n_items);
    // 3) cast W and x to bf16
    cvt_bf16_kernel<<<2048, 256, 0, stream>>>((const float4*)Wf, (ushort4*)Wb,
                                              (N_DIM * K_DIM) / 4);
    cvt_bf16_kernel<<<2048, 256, 0, stream>>>((const float4*)x, (ushort4*)Xb,
                                              (M_DIM * K_DIM) / 4);
    // 4) GEMM: out = Xb (M x K) * Wb (N x K)^T  -- 512 blocks of 512 threads
    gemm_bt<<<(M_DIM / 256) * (N_DIM / 256), 512, 0, stream>>>(Xb, Wb, out);
}

// Round 6
// 636.935 us; speedup vs baseline: 1.2190x; 1.2190x over previous
//
#include <hip/hip_runtime.h>
#include <hip/hip_bf16.h>

#define M_DIM 4096
#define N_DIM 8192
#define K_DIM 8192

using bf16x8 = __attribute__((ext_vector_type(8))) short;
using f32x4  = __attribute__((ext_vector_type(4))) float;
using v2s    = __attribute__((ext_vector_type(2))) short;

static __device__ __forceinline__ unsigned short f32_to_bf16_rne(float f) {
    unsigned u = __float_as_uint(f);
    unsigned rounding = 0x7FFFu + ((u >> 16) & 1u);
    u += rounding;
    return (unsigned short)(u >> 16);
}

// ---------------- zero (16B granules) ----------------
__global__ void zero_kernel(float4* __restrict__ p, int n4) {
    int i = blockIdx.x * blockDim.x + threadIdx.x;
    int stride = gridDim.x * blockDim.x;
    float4 z = make_float4(0.f, 0.f, 0.f, 0.f);
    for (; i < n4; i += stride) p[i] = z;
}

// ---------------- scatter-add COO directly into bf16 W ----------------
// W density is 6% (4M items / 67M cells); duplicates are rare (~0.2% of
// touched cells), so bf16 accumulation error (<=1 ulp on sums of ~2 values)
// is negligible vs the 2.52 threshold.  Native path: global_atomic_pk_add_bf16
// on the aligned bf16 pair (neighbor half gets +0.0, a no-op).  Fallback:
// 32-bit CAS loop (compile-safe everywhere, correct under contention).
__global__ void scatter_bf16_kernel(const float* __restrict__ vals,
                                    const int* __restrict__ rows,
                                    const int* __restrict__ cols,
                                    unsigned short* __restrict__ W, int n) {
    int i = blockIdx.x * blockDim.x + threadIdx.x;
    if (i >= n) return;
    size_t idx = (size_t)rows[i] * K_DIM + cols[i];
    unsigned* p = (unsigned*)W + (idx >> 1);
    const int hi = (int)(idx & 1);
#if __has_builtin(__builtin_amdgcn_global_atomic_fadd_v2bf16)
    unsigned short h = f32_to_bf16_rne(vals[i]);
    v2s pk;
    pk[0] = hi ? (short)0 : (short)h;
    pk[1] = hi ? (short)h : (short)0;
    __builtin_amdgcn_global_atomic_fadd_v2bf16(
        (__attribute__((address_space(1))) v2s*)p, pk);
#else
    float vf = vals[i];
    unsigned old = __hip_atomic_load(p, __ATOMIC_RELAXED, __HIP_MEMORY_SCOPE_AGENT);
    while (true) {
        unsigned cur = old;
        unsigned short th = hi ? (unsigned short)(cur >> 16)
                               : (unsigned short)(cur & 0xffffu);
        float f = __uint_as_float(((unsigned)th) << 16) + vf;
        unsigned short nh = f32_to_bf16_rne(f);
        unsigned nw = hi ? ((cur & 0x0000ffffu) | ((unsigned)nh << 16))
                         : ((cur & 0xffff0000u) | (unsigned)nh);
        unsigned prev = atomicCAS(p, cur, nw);
        if (prev == cur) break;
        old = prev;
    }
#endif
}

// ---------------- f32 -> bf16 cast (x only) ----------------
__global__ void cvt_bf16_kernel(const float4* __restrict__ src,
                                ushort4* __restrict__ dst, int n4) {
    int i = blockIdx.x * blockDim.x + threadIdx.x;
    int stride = gridDim.x * blockDim.x;
    for (; i < n4; i += stride) {
        float4 v = src[i];
        ushort4 o;
        o.x = f32_to_bf16_rne(v.x);
        o.y = f32_to_bf16_rne(v.y);
        o.z = f32_to_bf16_rne(v.z);
        o.w = f32_to_bf16_rne(v.w);
        dst[i] = o;
    }
}

// ---------------- zero d_out fallback (ws too small diagnostic) ----------------
__global__ void zero_out_kernel(float* __restrict__ p, int n) {
    int i = blockIdx.x * blockDim.x + threadIdx.x;
    int stride = gridDim.x * blockDim.x;
    for (; i < n; i += stride) p[i] = 0.f;
}

// ---------------- bf16 NT GEMM, 256x256 8-phase (T2+T3+T4+T5) ----------------
// r3's measured-good version (437 us, 1259 TF, SQ_LDS_BANK_CONFLICT = 0).
// The r4/r5 32x32x16 variant is REVERTED: its read shape carries an
// intrinsic 4 cyc/b128 conflict penalty (identical 5.033e7 under two
// different swizzles -> not pattern-fixable).
// C[M][N] = A[M][K] * B[N][K]^T.  BM=BN=256, BK=64, 8 waves (2M x 4N),
// per-wave output 128x64 (acc[8][4] f32x4).  LDS 128 KiB double-buffered.
// Per K-tile: 4 phases {ds_read subtile | stage 1 half-tile | barrier |
// lgkmcnt(0) | setprio(1) 16 MFMA setprio(0) | (boundary vmcnt) | barrier};
// vmcnt(4) only at tile boundaries.  Staging liveness:
//   p0: A(t+1) h0 -> db^1   p1: A(t+1) h1 -> db^1
//   p2: B(t+2) h0 -> db     p3: B(t+2) h1 -> db   (B[db] dead after p0)
// LDS swizzle (T2, rule #21): slot (row,c) holds global k-chunk c^(row&7);
// staging pre-swizzles the global source, reads apply the same involution.
__global__ __launch_bounds__(512, 2) void gemm_bt(const ushort* __restrict__ A,
                                                  const ushort* __restrict__ B,
                                                  float* __restrict__ C) {
    constexpr int BK = 64;
    constexpr int NT = K_DIM / BK;     // 128 K-tiles
    __shared__ ushort lds[65536];      // 128 KiB

    const int nbn = N_DIM / 256;       // 32
    const int bm = blockIdx.x / nbn;
    const int bn = blockIdx.x % nbn;
    const int brow = bm * 256, bcol = bn * 256;

    const int t    = threadIdx.x;
    const int lane = t & 63;
    const int wid  = t >> 6;           // 0..7
    const int wm   = wid >> 2;         // 0..1 (M)
    const int wn   = wid & 3;          // 0..3 (N)
    const int lrow = lane & 15;
    const int ghi  = lane >> 4;        // 0..3

    // read-side swizzled k-chunk per lane (row&7 == lrow&7)
    const int c0 = (0 + ghi) ^ (lrow & 7);   // ksub 0
    const int c1 = (4 + ghi) ^ (lrow & 7);   // ksub 1

    f32x4  acc[8][4] = {};
    bf16x8 bfr[4][2];                  // B frags, live across one tile

    auto stage_half = [&](int db, int op, int half, int ktile) {
        const ushort* G = (op == 0) ? A : B;
        const int rbase = ((op == 0) ? brow : bcol) + half * 128;
        #pragma unroll
        for (int i = 0; i < 2; ++i) {
            int fl  = i * 512 + t;                 // 0..1023
            int row = fl >> 3;
            int cc  = (fl & 7) ^ (row & 7);
            const ushort* src = G + (size_t)(rbase + row) * K_DIM + ktile * BK + cc * 8;
            __builtin_amdgcn_global_load_lds(
                (const __attribute__((address_space(1))) void*)src,
                (__attribute__((address_space(3))) void*)
                    (&lds[db * 32768 + op * 16384 + half * 8192 + fl * 8]),
                16, 0, 0);
        }
    };

    auto tile_body = [&](int tt, int db, bool stgA, bool stgB, int vm) {
        const ushort* Ah = &lds[db * 32768 + wm * 8192];
        const ushort* Bh = &lds[db * 32768 + 16384 + (wn >> 1) * 8192 + (wn & 1) * 4096];
        const ushort* a0 = Ah + lrow * 64 + c0 * 8;
        const ushort* a1 = Ah + lrow * 64 + c1 * 8;
        const ushort* b0 = Bh + lrow * 64 + c0 * 8;
        const ushort* b1 = Bh + lrow * 64 + c1 * 8;
        #pragma unroll
        for (int q = 0; q < 4; ++q) {
            bf16x8 af[2][2];
            if (q == 0) {
                #pragma unroll
                for (int n = 0; n < 4; ++n) {
                    bfr[n][0] = *(const bf16x8*)(b0 + n * 1024);
                    bfr[n][1] = *(const bf16x8*)(b1 + n * 1024);
                }
            }
            #pragma unroll
            for (int j = 0; j < 2; ++j) {
                af[j][0] = *(const bf16x8*)(a0 + (2 * q + j) * 1024);
                af[j][1] = *(const bf16x8*)(a1 + (2 * q + j) * 1024);
            }
            if (q == 0 && stgA) stage_half(db ^ 1, 0, 0, tt + 1);
            if (q == 1 && stgA) stage_half(db ^ 1, 0, 1, tt + 1);
            if (q == 2 && stgB) stage_half(db,     1, 0, tt + 2);
            if (q == 3 && stgB) stage_half(db,     1, 1, tt + 2);
            __builtin_amdgcn_s_barrier();
            asm volatile("s_waitcnt lgkmcnt(0)" ::: "memory");
            __builtin_amdgcn_s_setprio(1);
            #pragma unroll
            for (int j = 0; j < 2; ++j)
                #pragma unroll
                for (int n = 0; n < 4; ++n) {
                    acc[2 * q + j][n] = __builtin_amdgcn_mfma_f32_16x16x32_bf16(
                        af[j][0], bfr[n][0], acc[2 * q + j][n], 0, 0, 0);
                    acc[2 * q + j][n] = __builtin_amdgcn_mfma_f32_16x16x32_bf16(
                        af[j][1], bfr[n][1], acc[2 * q + j][n], 0, 0, 0);
                }
            __builtin_amdgcn_s_setprio(0);
            if (q == 3) {
                if (vm == 4) asm volatile("s_waitcnt vmcnt(4)" ::: "memory");
                else         asm volatile("s_waitcnt vmcnt(0)" ::: "memory");
            }
            __builtin_amdgcn_s_barrier();
        }
    };

    // ---- prologue: tile 0 fully + B(1); drain to 4 (B(1) stays in flight) ----
    stage_half(0, 0, 0, 0);
    stage_half(0, 0, 1, 0);
    stage_half(0, 1, 0, 0);
    stage_half(0, 1, 1, 0);
    stage_half(1, 1, 0, 1);
    stage_half(1, 1, 1, 1);
    asm volatile("s_waitcnt vmcnt(4)" ::: "memory");
    __builtin_amdgcn_s_barrier();

    // ---- main loop: tiles 0..NT-3 with full staging, vmcnt(4) ----
    for (int tt = 0; tt < NT - 2; tt += 2) {
        tile_body(tt,     0, true, true, 4);
        tile_body(tt + 1, 1, true, true, 4);
    }
    // ---- peeled tail: NT-2 stages A(NT-1) only then drains; NT-1 bare ----
    tile_body(NT - 2, 0, true,  false, 0);
    tile_body(NT - 1, 1, false, false, 0);

    // ---- epilogue: C/D layout col=lane&15, row=(lane>>4)*4+r ----
    const int crow0 = brow + wm * 128;
    const int ccol0 = bcol + wn * 64;
    #pragma unroll
    for (int m = 0; m < 8; ++m) {
        #pragma unroll
        for (int n = 0; n < 4; ++n) {
            int col   = ccol0 + n * 16 + lrow;
            int rbase = crow0 + m * 16 + (lane >> 4) * 4;
            #pragma unroll
            for (int r = 0; r < 4; ++r)
                C[(size_t)(rbase + r) * N_DIM + col] = acc[m][n][r];
        }
    }
}

extern "C" void kernel_launch(void* const* d_in, const int* in_sizes, int n_in,
                              void* d_out, int out_size, void* d_ws, size_t ws_size,
                              hipStream_t stream) {
    const float* x    = (const float*)d_in[0];
    const float* vals = (const float*)d_in[1];
    const int* rows   = (const int*)d_in[2];
    const int* cols   = (const int*)d_in[3];
    float* out        = (float*)d_out;
    const int n_items = in_sizes[1];

    const size_t W_BF16_BYTES = (size_t)N_DIM * K_DIM * 2;  // 128 MiB
    const size_t X_BF16_BYTES = (size_t)M_DIM * K_DIM * 2;  //  64 MiB
    const size_t NEEDED = W_BF16_BYTES + X_BF16_BYTES;      // 192 MiB

    if (ws_size < NEEDED) {
        // Diagnostic fallback: clean absmax=126 failure signals ws too small.
        zero_out_kernel<<<2048, 256, 0, stream>>>(out, out_size);
        return;
    }

    char* ws = (char*)d_ws;
    unsigned short* Wb = (unsigned short*)ws;
    ushort* Xb = (ushort*)(ws + W_BF16_BYTES);

    // 1) zero bf16 W (128 MiB; re-zeroed every call: deterministic under replay)
    zero_kernel<<<2048, 256, 0, stream>>>((float4*)Wb,
                                          (int)(W_BF16_BYTES / 16));
    // 2) scatter-add nonzeros directly in bf16 (pk_add_bf16 / CAS fallback)
    scatter_bf16_kernel<<<(n_items + 255) / 256, 256, 0, stream>>>(
        vals, rows, cols, Wb, n_items);
    // 3) cast x to bf16
    cvt_bf16_kernel<<<2048, 256, 0, stream>>>((const float4*)x, (ushort4*)Xb,
                                              (M_DIM * K_DIM) / 4);
    // 4) GEMM: out = Xb (M x K) * Wb (N x K)^T  -- 512 blocks of 512 threads
    gemm_bt<<<(M_DIM / 256) * (N_DIM / 256), 512, 0, stream>>>(
        Xb, (const ushort*)Wb, out);
}